// Round 1
// baseline (716.357 us; speedup 1.0000x reference)
//
#include <hip/hip_runtime.h>
#include <hip/hip_bf16.h>

typedef __attribute__((ext_vector_type(8))) short s8v;
typedef __attribute__((ext_vector_type(4))) float f4v;

__device__ __forceinline__ ushort bf16_rne(float f) {
    uint u = __float_as_uint(f);
    return (ushort)((u + 0x7FFFu + ((u >> 16) & 1u)) >> 16);
}
__device__ __forceinline__ float bf16_to_f32(ushort h) {
    return __uint_as_float(((uint)h) << 16);
}

#define GL2LDS16(g, l) __builtin_amdgcn_global_load_lds( \
    (const __attribute__((address_space(1))) void*)(g),  \
    (__attribute__((address_space(3))) void*)(l), 16, 0, 0)

// ---------------- gate: alpha = softmax(x @ gate_W + gate_b) ----------------
__global__ __launch_bounds__(256) void gate_kernel(
    const float* __restrict__ x, const float* __restrict__ gW,
    const float* __restrict__ gb, float* __restrict__ alpha)
{
    int lane = threadIdx.x & 63;
    int wave = threadIdx.x >> 6;
    int row = blockIdx.x * 4 + wave;
    float4 xv = *(const float4*)(x + (size_t)row * 256 + lane * 4);
    const float* xp = (const float*)&xv;
    float p[8];
#pragma unroll
    for (int k = 0; k < 8; ++k) p[k] = 0.f;
#pragma unroll
    for (int j = 0; j < 4; ++j) {
        float xs = xp[j];
        const float* wr = gW + (lane * 4 + j) * 8;
#pragma unroll
        for (int k = 0; k < 8; ++k) p[k] = fmaf(xs, wr[k], p[k]);
    }
#pragma unroll
    for (int off = 32; off > 0; off >>= 1) {
#pragma unroll
        for (int k = 0; k < 8; ++k) p[k] += __shfl_xor(p[k], off);
    }
    float m = -1e30f;
#pragma unroll
    for (int k = 0; k < 8; ++k) { p[k] += gb[k]; m = fmaxf(m, p[k]); }
    float s = 0.f;
#pragma unroll
    for (int k = 0; k < 8; ++k) { p[k] = expf(p[k] - m); s += p[k]; }
    if (lane < 8) alpha[(size_t)row * 8 + lane] = p[lane] / s;
}

// ---- weight prep: transpose to [mat][o][i] + split f32 -> bf16 hi/lo ------
// mats 0..31 = block_W (L=4, K=8), mats 32..39 = out_W (K=8)
__global__ __launch_bounds__(256) void prep_weights(
    const float* __restrict__ blockW, const float* __restrict__ outW,
    ushort* __restrict__ Whi, ushort* __restrict__ Wlo)
{
    int mat = blockIdx.x >> 4;
    int tile = blockIdx.x & 15;
    int i0 = (tile >> 2) * 64, o0 = (tile & 3) * 64;
    const float* src = (mat < 32) ? (blockW + (size_t)mat * 65536)
                                  : (outW + (size_t)(mat - 32) * 65536);
    __shared__ float tl[64][65];
    int r = threadIdx.x >> 2, c0 = (threadIdx.x & 3) * 16;
#pragma unroll
    for (int e = 0; e < 16; e += 4) {
        float4 v = *(const float4*)(src + (size_t)(i0 + r) * 256 + o0 + c0 + e);
        tl[r][c0 + e + 0] = v.x; tl[r][c0 + e + 1] = v.y;
        tl[r][c0 + e + 2] = v.z; tl[r][c0 + e + 3] = v.w;
    }
    __syncthreads();
    int oc = threadIdx.x >> 2, ic0 = (threadIdx.x & 3) * 16;
    uint hp[8], lp[8];
#pragma unroll
    for (int e = 0; e < 16; e += 2) {
        float f0 = tl[ic0 + e][oc], f1 = tl[ic0 + e + 1][oc];
        ushort h0 = bf16_rne(f0), h1 = bf16_rne(f1);
        ushort l0 = bf16_rne(f0 - bf16_to_f32(h0));
        ushort l1 = bf16_rne(f1 - bf16_to_f32(h1));
        hp[e >> 1] = (uint)h0 | ((uint)h1 << 16);
        lp[e >> 1] = (uint)l0 | ((uint)l1 << 16);
    }
    size_t base = ((size_t)(mat * 256 + o0 + oc)) * 256 + i0 + ic0;
    *(uint4*)(Whi + base)     = make_uint4(hp[0], hp[1], hp[2], hp[3]);
    *(uint4*)(Whi + base + 8) = make_uint4(hp[4], hp[5], hp[6], hp[7]);
    *(uint4*)(Wlo + base)     = make_uint4(lp[0], lp[1], lp[2], lp[3]);
    *(uint4*)(Wlo + base + 8) = make_uint4(lp[4], lp[5], lp[6], lp[7]);
}

// ------------- fused MoIE layer: Hout = act(Hx @ W' + alpha.b) -------------
// BM=128, BN=256 (full width -> in-place safe), BK=32, 512 thr (2x4 waves)
template<bool RELU>
__global__ __launch_bounds__(512) void moie_gemm(
    const float* Hin, float* Hout,
    const ushort* __restrict__ Whi, const ushort* __restrict__ Wlo,
    const float* __restrict__ bias, const float* __restrict__ alpha)
{
    __shared__ __align__(16) ushort Ahi[128 * 32], Alo[128 * 32];
    __shared__ __align__(16) ushort Bhi[256 * 32], Blo[256 * 32];
    __shared__ float bias_lds[8 * 256];

    const int tid  = threadIdx.x;
    const int lane = tid & 63;
    const int wid  = tid >> 6;
    const int m0   = blockIdx.x * 128;
    const int wrow0 = (wid >> 2) * 64;
    const int wcol0 = (wid & 3) * 64;

    for (int i = tid; i < 2048; i += 512) bias_lds[i] = bias[i];

    f4v acc[4][4];
#pragma unroll
    for (int a = 0; a < 4; ++a)
#pragma unroll
        for (int b = 0; b < 4; ++b) acc[a][b] = (f4v){0.f, 0.f, 0.f, 0.f};

    // A staging: thread -> (row, 8-col group), swizzle kg' = kg ^ ((r>>1)&3)
    const int ar  = tid >> 2;
    const int akg = tid & 3;
    ushort* aw_hi = Ahi + ar * 32 + (akg ^ ((ar >> 1) & 3)) * 8;
    ushort* aw_lo = Alo + ar * 32 + (akg ^ ((ar >> 1) & 3)) * 8;
    const float* arow = Hin + (size_t)(m0 + ar) * 256 + akg * 8;
    const float* aal  = alpha + (size_t)(m0 + ar) * 8;

    // fragment read offsets (fixed per lane)
    const int kgl = lane >> 4;
    const int fr  = lane & 15;
    int aoff[4], boff[4];
#pragma unroll
    for (int im = 0; im < 4; ++im) {
        int r = wrow0 + im * 16 + fr;
        aoff[im] = r * 32 + (kgl ^ ((r >> 1) & 3)) * 8;
    }
#pragma unroll
    for (int in = 0; in < 4; ++in) {
        int n = wcol0 + in * 16 + fr;
        boff[in] = n * 32 + (kgl ^ ((n >> 1) & 3)) * 8;
    }

    // B staging chunks: c = (q*8+wid)*64 + lane; LDS linear, source pre-swizzled
    int bgoff[2];
#pragma unroll
    for (int q = 0; q < 2; ++q) {
        int c = (q * 8 + wid) * 64 + lane;
        int n = c >> 2;
        int kg = (c & 3) ^ ((n >> 1) & 3);
        bgoff[q] = n * 256 + kg * 8;
    }

#pragma unroll 1
    for (int kk = 0; kk < 2048; kk += 32) {
        const int kexp = kk >> 8;
        const int ki0  = kk & 255;
        __syncthreads();
        // B stage: async global->LDS (already bf16 hi/lo, pre-transposed)
#pragma unroll
        for (int q = 0; q < 2; ++q) {
            size_t g = (size_t)kexp * 65536 + bgoff[q] + ki0;
            GL2LDS16(Whi + g, Bhi + (q * 8 + wid) * 512);
            GL2LDS16(Wlo + g, Blo + (q * 8 + wid) * 512);
        }
        // A stage: f32 load, scale by alpha, split hi/lo, ds_write_b128
        {
            float4 v0 = *(const float4*)(arow + ki0);
            float4 v1 = *(const float4*)(arow + ki0 + 4);
            float asc = aal[kexp];
            float f[8] = {v0.x, v0.y, v0.z, v0.w, v1.x, v1.y, v1.z, v1.w};
            uint hp[4], lp[4];
#pragma unroll
            for (int e = 0; e < 8; e += 2) {
                float f0 = f[e] * asc, f1 = f[e + 1] * asc;
                ushort h0 = bf16_rne(f0), h1 = bf16_rne(f1);
                ushort l0 = bf16_rne(f0 - bf16_to_f32(h0));
                ushort l1 = bf16_rne(f1 - bf16_to_f32(h1));
                hp[e >> 1] = (uint)h0 | ((uint)h1 << 16);
                lp[e >> 1] = (uint)l0 | ((uint)l1 << 16);
            }
            *(uint4*)aw_hi = make_uint4(hp[0], hp[1], hp[2], hp[3]);
            *(uint4*)aw_lo = make_uint4(lp[0], lp[1], lp[2], lp[3]);
        }
        __syncthreads();
        // compute: 16 frag pairs x 3 split products
        s8v afh[4], afl[4], bfh[4], bfl[4];
#pragma unroll
        for (int im = 0; im < 4; ++im) {
            afh[im] = *(const s8v*)(Ahi + aoff[im]);
            afl[im] = *(const s8v*)(Alo + aoff[im]);
        }
#pragma unroll
        for (int in = 0; in < 4; ++in) {
            bfh[in] = *(const s8v*)(Bhi + boff[in]);
            bfl[in] = *(const s8v*)(Blo + boff[in]);
        }
#pragma unroll
        for (int im = 0; im < 4; ++im) {
#pragma unroll
            for (int in = 0; in < 4; ++in) {
                acc[im][in] = __builtin_amdgcn_mfma_f32_16x16x32_bf16(afh[im], bfh[in], acc[im][in], 0, 0, 0);
                acc[im][in] = __builtin_amdgcn_mfma_f32_16x16x32_bf16(afh[im], bfl[in], acc[im][in], 0, 0, 0);
                acc[im][in] = __builtin_amdgcn_mfma_f32_16x16x32_bf16(afl[im], bfh[in], acc[im][in], 0, 0, 0);
            }
        }
    }

    // epilogue: + sum_k alpha[b,k]*bias[k,o], optional relu, f32 store
    float bv[4][8];
#pragma unroll
    for (int in = 0; in < 4; ++in) {
        int col = wcol0 + in * 16 + fr;
#pragma unroll
        for (int k = 0; k < 8; ++k) bv[in][k] = bias_lds[k * 256 + col];
    }
#pragma unroll
    for (int im = 0; im < 4; ++im) {
#pragma unroll
        for (int j = 0; j < 4; ++j) {
            int row = m0 + wrow0 + im * 16 + kgl * 4 + j;
            float a8[8];
#pragma unroll
            for (int k = 0; k < 8; ++k) a8[k] = alpha[(size_t)row * 8 + k];
#pragma unroll
            for (int in = 0; in < 4; ++in) {
                int col = wcol0 + in * 16 + fr;
                float be = 0.f;
#pragma unroll
                for (int k = 0; k < 8; ++k) be = fmaf(a8[k], bv[in][k], be);
                float v = acc[im][in][j] + be;
                if (RELU) v = fmaxf(v, 0.f);
                Hout[(size_t)row * 256 + col] = v;
            }
        }
    }
}

extern "C" void kernel_launch(void* const* d_in, const int* in_sizes, int n_in,
                              void* d_out, int out_size, void* d_ws, size_t ws_size,
                              hipStream_t stream)
{
    const float* x      = (const float*)d_in[0];
    const float* gW     = (const float*)d_in[1];
    const float* gb     = (const float*)d_in[2];
    const float* blockW = (const float*)d_in[3];
    const float* blockB = (const float*)d_in[4];
    const float* outW   = (const float*)d_in[5];
    const float* outB   = (const float*)d_in[6];
    float* out = (float*)d_out;

    char* ws = (char*)d_ws;
    float*  alpha = (float*)ws;                         // 32768*8*4 = 1 MB
    ushort* Whi   = (ushort*)(ws + (1 << 20));          // 40*65536*2B = 5.25 MB
    ushort* Wlo   = Whi + (size_t)40 * 65536;           // 5.25 MB

    prep_weights<<<640, 256, 0, stream>>>(blockW, outW, Whi, Wlo);
    gate_kernel<<<8192, 256, 0, stream>>>(x, gW, gb, alpha);

    const size_t WL = (size_t)8 * 65536;
    moie_gemm<true ><<<256, 512, 0, stream>>>(x,   out, Whi,          Wlo,          blockB,          alpha);
    moie_gemm<true ><<<256, 512, 0, stream>>>(out, out, Whi + 1 * WL, Wlo + 1 * WL, blockB + 1 * 2048, alpha);
    moie_gemm<true ><<<256, 512, 0, stream>>>(out, out, Whi + 2 * WL, Wlo + 2 * WL, blockB + 2 * 2048, alpha);
    moie_gemm<true ><<<256, 512, 0, stream>>>(out, out, Whi + 3 * WL, Wlo + 3 * WL, blockB + 3 * 2048, alpha);
    moie_gemm<false><<<256, 512, 0, stream>>>(out, out, Whi + 4 * WL, Wlo + 4 * WL, outB,            alpha);
}

// Round 2
// 500.146 us; speedup vs baseline: 1.4323x; 1.4323x over previous
//
#include <hip/hip_runtime.h>
#include <hip/hip_bf16.h>

typedef __attribute__((ext_vector_type(8))) _Float16 h8v;
typedef __attribute__((ext_vector_type(4))) float f4v;

__device__ __forceinline__ ushort f16bits(float f) {
    _Float16 h = (_Float16)f;
    return __builtin_bit_cast(unsigned short, h);
}
__device__ __forceinline__ float f16val(ushort u) {
    _Float16 h = __builtin_bit_cast(_Float16, u);
    return (float)h;
}

#define GL2LDS16(g, l) __builtin_amdgcn_global_load_lds( \
    (const __attribute__((address_space(1))) void*)(g),  \
    (__attribute__((address_space(3))) void*)(l), 16, 0, 0)

// ---------------- gate: alpha = softmax(x @ gate_W + gate_b) ----------------
__global__ __launch_bounds__(256) void gate_kernel(
    const float* __restrict__ x, const float* __restrict__ gW,
    const float* __restrict__ gb, float* __restrict__ alpha)
{
    int lane = threadIdx.x & 63;
    int wave = threadIdx.x >> 6;
    int row = blockIdx.x * 4 + wave;
    float4 xv = *(const float4*)(x + (size_t)row * 256 + lane * 4);
    const float* xp = (const float*)&xv;
    float p[8];
#pragma unroll
    for (int k = 0; k < 8; ++k) p[k] = 0.f;
#pragma unroll
    for (int j = 0; j < 4; ++j) {
        float xs = xp[j];
        const float* wr = gW + (lane * 4 + j) * 8;
#pragma unroll
        for (int k = 0; k < 8; ++k) p[k] = fmaf(xs, wr[k], p[k]);
    }
#pragma unroll
    for (int off = 32; off > 0; off >>= 1) {
#pragma unroll
        for (int k = 0; k < 8; ++k) p[k] += __shfl_xor(p[k], off);
    }
    float m = -1e30f;
#pragma unroll
    for (int k = 0; k < 8; ++k) { p[k] += gb[k]; m = fmaxf(m, p[k]); }
    float s = 0.f;
#pragma unroll
    for (int k = 0; k < 8; ++k) { p[k] = expf(p[k] - m); s += p[k]; }
    if (lane < 8) alpha[(size_t)row * 8 + lane] = p[lane] / s;
}

// ---- weight prep: transpose to [mat][o][i] + convert f32 -> fp16 ----------
// mats 0..31 = block_W (L=4, K=8), mats 32..39 = out_W (K=8)
__global__ __launch_bounds__(256) void prep_weights(
    const float* __restrict__ blockW, const float* __restrict__ outW,
    ushort* __restrict__ Wh)
{
    int mat = blockIdx.x >> 4;
    int tile = blockIdx.x & 15;
    int i0 = (tile >> 2) * 64, o0 = (tile & 3) * 64;
    const float* src = (mat < 32) ? (blockW + (size_t)mat * 65536)
                                  : (outW + (size_t)(mat - 32) * 65536);
    __shared__ float tl[64][65];
    int r = threadIdx.x >> 2, c0 = (threadIdx.x & 3) * 16;
#pragma unroll
    for (int e = 0; e < 16; e += 4) {
        float4 v = *(const float4*)(src + (size_t)(i0 + r) * 256 + o0 + c0 + e);
        tl[r][c0 + e + 0] = v.x; tl[r][c0 + e + 1] = v.y;
        tl[r][c0 + e + 2] = v.z; tl[r][c0 + e + 3] = v.w;
    }
    __syncthreads();
    int oc = threadIdx.x >> 2, ic0 = (threadIdx.x & 3) * 16;
    uint hp[8];
#pragma unroll
    for (int e = 0; e < 16; e += 2) {
        ushort h0 = f16bits(tl[ic0 + e][oc]);
        ushort h1 = f16bits(tl[ic0 + e + 1][oc]);
        hp[e >> 1] = (uint)h0 | ((uint)h1 << 16);
    }
    size_t base = ((size_t)(mat * 256 + o0 + oc)) * 256 + i0 + ic0;
    *(uint4*)(Wh + base)     = make_uint4(hp[0], hp[1], hp[2], hp[3]);
    *(uint4*)(Wh + base + 8) = make_uint4(hp[4], hp[5], hp[6], hp[7]);
}

// ------------- fused MoIE layer: Hout = act(Hx @ W' + alpha.b) -------------
// BM=64, BN=256 (full width -> in-place safe), BK=32, 256 thr (4 waves 1x4),
// wave tile 64x64, fp16 2-term (A hi/lo, B single), double-buffered LDS.
template<bool RELU>
__global__ __launch_bounds__(256, 2) void moie_gemm(
    const float* __restrict__ Hin, float* __restrict__ Hout,
    const ushort* __restrict__ Wh,
    const float* __restrict__ bias, const float* __restrict__ alpha)
{
    __shared__ __align__(16) ushort Ahi[2][64 * 32];
    __shared__ __align__(16) ushort Alo[2][64 * 32];
    __shared__ __align__(16) ushort Bh[2][256 * 32];
    __shared__ float bias_lds[2048];

    const int tid  = threadIdx.x;
    const int lane = tid & 63;
    const int wid  = tid >> 6;
    const int m0   = blockIdx.x * 64;
    const int wcol0 = wid * 64;

    for (int i = tid; i < 2048; i += 256) bias_lds[i] = bias[i];

    f4v acc[4][4];
#pragma unroll
    for (int a = 0; a < 4; ++a)
#pragma unroll
        for (int b = 0; b < 4; ++b) acc[a][b] = (f4v){0.f, 0.f, 0.f, 0.f};

    // A staging map: thread -> (row = tid>>2, 8-col group = tid&3)
    const int ar   = tid >> 2;
    const int akg  = tid & 3;
    const int aw_off = ar * 32 + (akg ^ ((ar >> 1) & 3)) * 8;
    const float* arow = Hin + (size_t)(m0 + ar) * 256 + akg * 8;
    const float* aal  = alpha + (size_t)(m0 + ar) * 8;

    // B staging source offsets (LDS linear, global pre-swizzled)
    int bgoff[4];
#pragma unroll
    for (int q = 0; q < 4; ++q) {
        int c = q * 256 + tid;
        int n = c >> 2;
        int kg = (c & 3) ^ ((n >> 1) & 3);
        bgoff[q] = n * 256 + kg * 8;
    }

    // fragment read offsets
    const int kgl = lane >> 4;
    const int fr  = lane & 15;
    int aoff[4], boff[4];
#pragma unroll
    for (int im = 0; im < 4; ++im) {
        int r = im * 16 + fr;
        aoff[im] = r * 32 + (kgl ^ ((r >> 1) & 3)) * 8;
    }
#pragma unroll
    for (int in = 0; in < 4; ++in) {
        int n = wcol0 + in * 16 + fr;
        boff[in] = n * 32 + (kgl ^ ((n >> 1) & 3)) * 8;
    }

    // ---- prologue: load A(k=0), stage buf0, prefetch A(k=32) ----
    float4 av0 = *(const float4*)(arow);
    float4 av1 = *(const float4*)(arow + 4);
    float asc  = aal[0];

#pragma unroll
    for (int q = 0; q < 4; ++q)
        GL2LDS16(Wh + bgoff[q], &Bh[0][(q * 256 + wid * 64) * 8]);
    {
        float f[8] = {av0.x, av0.y, av0.z, av0.w, av1.x, av1.y, av1.z, av1.w};
        uint hp[4], lp[4];
#pragma unroll
        for (int e = 0; e < 8; e += 2) {
            float a0 = f[e] * asc, a1 = f[e + 1] * asc;
            ushort h0 = f16bits(a0), h1 = f16bits(a1);
            ushort l0 = f16bits(a0 - f16val(h0));
            ushort l1 = f16bits(a1 - f16val(h1));
            hp[e >> 1] = (uint)h0 | ((uint)h1 << 16);
            lp[e >> 1] = (uint)l0 | ((uint)l1 << 16);
        }
        *(uint4*)&Ahi[0][aw_off] = make_uint4(hp[0], hp[1], hp[2], hp[3]);
        *(uint4*)&Alo[0][aw_off] = make_uint4(lp[0], lp[1], lp[2], lp[3]);
    }
    av0 = *(const float4*)(arow + 32);
    av1 = *(const float4*)(arow + 36);
    asc = aal[0];

#pragma unroll 1
    for (int t = 0; t < 64; ++t) {
        const int cur = t & 1;
        __syncthreads();   // publishes buf[cur]; guards overwrite of buf[cur^1]
        if (t < 63) {
            const int kk   = (t + 1) * 32;
            const int kexp = kk >> 8;
            const int ki0  = kk & 255;
            // stage B(t+1) async global->LDS
#pragma unroll
            for (int q = 0; q < 4; ++q)
                GL2LDS16(Wh + (size_t)kexp * 65536 + bgoff[q] + ki0,
                         &Bh[cur ^ 1][(q * 256 + wid * 64) * 8]);
            // stage A(t+1) from prefetched regs: scale, fp16 hi/lo split
            {
                float f[8] = {av0.x, av0.y, av0.z, av0.w, av1.x, av1.y, av1.z, av1.w};
                uint hp[4], lp[4];
#pragma unroll
                for (int e = 0; e < 8; e += 2) {
                    float a0 = f[e] * asc, a1 = f[e + 1] * asc;
                    ushort h0 = f16bits(a0), h1 = f16bits(a1);
                    ushort l0 = f16bits(a0 - f16val(h0));
                    ushort l1 = f16bits(a1 - f16val(h1));
                    hp[e >> 1] = (uint)h0 | ((uint)h1 << 16);
                    lp[e >> 1] = (uint)l0 | ((uint)l1 << 16);
                }
                *(uint4*)&Ahi[cur ^ 1][aw_off] = make_uint4(hp[0], hp[1], hp[2], hp[3]);
                *(uint4*)&Alo[cur ^ 1][aw_off] = make_uint4(lp[0], lp[1], lp[2], lp[3]);
            }
            // prefetch A(t+2)
            if (t < 62) {
                const int kk2 = (t + 2) * 32;
                const int ki2 = kk2 & 255;
                av0 = *(const float4*)(arow + ki2);
                av1 = *(const float4*)(arow + ki2 + 4);
                asc = aal[kk2 >> 8];
            }
        }
        // compute tile t from buf[cur]
        h8v afh[4], afl[4], bf[4];
#pragma unroll
        for (int im = 0; im < 4; ++im) {
            afh[im] = *(const h8v*)&Ahi[cur][aoff[im]];
            afl[im] = *(const h8v*)&Alo[cur][aoff[im]];
        }
#pragma unroll
        for (int in = 0; in < 4; ++in)
            bf[in] = *(const h8v*)&Bh[cur][boff[in]];
#pragma unroll
        for (int im = 0; im < 4; ++im) {
#pragma unroll
            for (int in = 0; in < 4; ++in) {
                acc[im][in] = __builtin_amdgcn_mfma_f32_16x16x32_f16(afh[im], bf[in], acc[im][in], 0, 0, 0);
                acc[im][in] = __builtin_amdgcn_mfma_f32_16x16x32_f16(afl[im], bf[in], acc[im][in], 0, 0, 0);
            }
        }
    }

    // epilogue: + sum_k alpha[b,k]*bias[k,o], optional relu, f32 store
    float bv[4][8];
#pragma unroll
    for (int in = 0; in < 4; ++in) {
        int col = wcol0 + in * 16 + fr;
#pragma unroll
        for (int k = 0; k < 8; ++k) bv[in][k] = bias_lds[k * 256 + col];
    }
#pragma unroll
    for (int im = 0; im < 4; ++im) {
#pragma unroll
        for (int j = 0; j < 4; ++j) {
            int row = m0 + im * 16 + kgl * 4 + j;
            const float4* ap = (const float4*)(alpha + (size_t)row * 8);
            float4 a0 = ap[0], a1 = ap[1];
            float a8[8] = {a0.x, a0.y, a0.z, a0.w, a1.x, a1.y, a1.z, a1.w};
#pragma unroll
            for (int in = 0; in < 4; ++in) {
                int col = wcol0 + in * 16 + fr;
                float be = 0.f;
#pragma unroll
                for (int k = 0; k < 8; ++k) be = fmaf(a8[k], bv[in][k], be);
                float v = acc[im][in][j] + be;
                if (RELU) v = fmaxf(v, 0.f);
                Hout[(size_t)row * 256 + col] = v;
            }
        }
    }
}

extern "C" void kernel_launch(void* const* d_in, const int* in_sizes, int n_in,
                              void* d_out, int out_size, void* d_ws, size_t ws_size,
                              hipStream_t stream)
{
    const float* x      = (const float*)d_in[0];
    const float* gW     = (const float*)d_in[1];
    const float* gb     = (const float*)d_in[2];
    const float* blockW = (const float*)d_in[3];
    const float* blockB = (const float*)d_in[4];
    const float* outW   = (const float*)d_in[5];
    const float* outB   = (const float*)d_in[6];
    float* out = (float*)d_out;

    char* ws = (char*)d_ws;
    float*  alpha = (float*)ws;                 // 32768*8*4 = 1 MB
    ushort* Wh    = (ushort*)(ws + (1 << 20));  // 40*65536*2B = 5.25 MB

    prep_weights<<<640, 256, 0, stream>>>(blockW, outW, Wh);
    gate_kernel<<<8192, 256, 0, stream>>>(x, gW, gb, alpha);

    const size_t WL = (size_t)8 * 65536;
    moie_gemm<true ><<<512, 256, 0, stream>>>(x,   out, Wh,          blockB,            alpha);
    moie_gemm<true ><<<512, 256, 0, stream>>>(out, out, Wh + 1 * WL, blockB + 1 * 2048, alpha);
    moie_gemm<true ><<<512, 256, 0, stream>>>(out, out, Wh + 2 * WL, blockB + 2 * 2048, alpha);
    moie_gemm<true ><<<512, 256, 0, stream>>>(out, out, Wh + 3 * WL, blockB + 3 * 2048, alpha);
    moie_gemm<false><<<512, 256, 0, stream>>>(out, out, Wh + 4 * WL, outB,              alpha);
}

// Round 3
// 290.728 us; speedup vs baseline: 2.4640x; 1.7203x over previous
//
#include <hip/hip_runtime.h>
#include <hip/hip_bf16.h>

typedef __attribute__((ext_vector_type(8))) _Float16 h8v;
typedef __attribute__((ext_vector_type(4))) float f4v;

__device__ __forceinline__ ushort f16bits(float f) {
    _Float16 h = (_Float16)f;
    return __builtin_bit_cast(unsigned short, h);
}

#define GL2LDS16(g, l) __builtin_amdgcn_global_load_lds( \
    (const __attribute__((address_space(1))) void*)(g),  \
    (__attribute__((address_space(3))) void*)(l), 16, 0, 0)

// ---------------- gate: alpha = softmax(x @ gate_W + gate_b) ----------------
__global__ __launch_bounds__(256) void gate_kernel(
    const float* __restrict__ x, const float* __restrict__ gW,
    const float* __restrict__ gb, float* __restrict__ alpha)
{
    int lane = threadIdx.x & 63;
    int wave = threadIdx.x >> 6;
    int row = blockIdx.x * 4 + wave;
    float4 xv = *(const float4*)(x + (size_t)row * 256 + lane * 4);
    const float* xp = (const float*)&xv;
    float p[8];
#pragma unroll
    for (int k = 0; k < 8; ++k) p[k] = 0.f;
#pragma unroll
    for (int j = 0; j < 4; ++j) {
        float xs = xp[j];
        const float* wr = gW + (lane * 4 + j) * 8;
#pragma unroll
        for (int k = 0; k < 8; ++k) p[k] = fmaf(xs, wr[k], p[k]);
    }
#pragma unroll
    for (int off = 32; off > 0; off >>= 1) {
#pragma unroll
        for (int k = 0; k < 8; ++k) p[k] += __shfl_xor(p[k], off);
    }
    float m = -1e30f;
#pragma unroll
    for (int k = 0; k < 8; ++k) { p[k] += gb[k]; m = fmaxf(m, p[k]); }
    float s = 0.f;
#pragma unroll
    for (int k = 0; k < 8; ++k) { p[k] = expf(p[k] - m); s += p[k]; }
    if (lane < 8) alpha[(size_t)row * 8 + lane] = p[lane] / s;
}

// ---- weight prep: transpose to [mat][o][i] + convert f32 -> fp16 ----------
// mats 0..31 = block_W (L=4, K=8), mats 32..39 = out_W (K=8)
__global__ __launch_bounds__(256) void prep_weights(
    const float* __restrict__ blockW, const float* __restrict__ outW,
    ushort* __restrict__ Wh)
{
    int mat = blockIdx.x >> 4;
    int tile = blockIdx.x & 15;
    int i0 = (tile >> 2) * 64, o0 = (tile & 3) * 64;
    const float* src = (mat < 32) ? (blockW + (size_t)mat * 65536)
                                  : (outW + (size_t)(mat - 32) * 65536);
    __shared__ float tl[64][65];
    int r = threadIdx.x >> 2, c0 = (threadIdx.x & 3) * 16;
#pragma unroll
    for (int e = 0; e < 16; e += 4) {
        float4 v = *(const float4*)(src + (size_t)(i0 + r) * 256 + o0 + c0 + e);
        tl[r][c0 + e + 0] = v.x; tl[r][c0 + e + 1] = v.y;
        tl[r][c0 + e + 2] = v.z; tl[r][c0 + e + 3] = v.w;
    }
    __syncthreads();
    int oc = threadIdx.x >> 2, ic0 = (threadIdx.x & 3) * 16;
    uint hp[8];
#pragma unroll
    for (int e = 0; e < 16; e += 2) {
        ushort h0 = f16bits(tl[ic0 + e][oc]);
        ushort h1 = f16bits(tl[ic0 + e + 1][oc]);
        hp[e >> 1] = (uint)h0 | ((uint)h1 << 16);
    }
    size_t base = ((size_t)(mat * 256 + o0 + oc)) * 256 + i0 + ic0;
    *(uint4*)(Wh + base)     = make_uint4(hp[0], hp[1], hp[2], hp[3]);
    *(uint4*)(Wh + base + 8) = make_uint4(hp[4], hp[5], hp[6], hp[7]);
}

// ------------- fused MoIE layer, expert-major A reuse ----------------------
// BM=64, BN=256 (full width -> in-place safe), 256 thr (4 waves 1x4),
// wave tile 64x64. A tile (64x256 fp16) resident in LDS, staged once.
// Loop t=0..63: ki = t>>3 (A frags cached in regs, refreshed per ki),
// e = t&7 (alpha applied per-expert via v_pk_mul_f16). B double-buffered.
template<bool RELU>
__global__ __launch_bounds__(256, 2) void moie_gemm(
    const float* __restrict__ Hin, float* __restrict__ Hout,
    const ushort* __restrict__ Wh,
    const float* __restrict__ bias, const float* __restrict__ alpha)
{
    __shared__ __align__(16) ushort Ah[64 * 256];     // 32 KB, swizzled
    __shared__ __align__(16) ushort Bh[2][256 * 32];  // 32 KB

    const int tid  = threadIdx.x;
    const int lane = tid & 63;
    const int wid  = tid >> 6;
    const int m0   = blockIdx.x * 64;
    const int wcol0 = wid * 64;
    const int kgl = lane >> 4;   // 0..3
    const int fr  = lane & 15;

    // ---- alpha for frag scaling: rows im*16+fr, all 8 experts -> 32 regs ----
    float areg[4][8];
#pragma unroll
    for (int im = 0; im < 4; ++im) {
        const float4* ap = (const float4*)(alpha + (size_t)(m0 + im * 16 + fr) * 8);
        float4 a0 = ap[0], a1 = ap[1];
        areg[im][0] = a0.x; areg[im][1] = a0.y; areg[im][2] = a0.z; areg[im][3] = a0.w;
        areg[im][4] = a1.x; areg[im][5] = a1.y; areg[im][6] = a1.z; areg[im][7] = a1.w;
    }

    // ---- B staging source offsets (LDS linear, global pre-swizzled) ----
    int bgoff[4];
#pragma unroll
    for (int q = 0; q < 4; ++q) {
        int c = q * 256 + tid;
        int n = c >> 2;
        int kg = (c & 3) ^ ((n >> 1) & 3);
        bgoff[q] = n * 256 + kg * 8;
    }
    // B fragment read offsets
    int boff[4];
#pragma unroll
    for (int in = 0; in < 4; ++in) {
        int n = wcol0 + in * 16 + fr;
        boff[in] = n * 32 + (kgl ^ ((n >> 1) & 3)) * 8;
    }

    // ---- prologue: stage B(t=0) ----
#pragma unroll
    for (int q = 0; q < 4; ++q)
        GL2LDS16(Wh + bgoff[q], &Bh[0][(q * 256 + wid * 64) * 8]);

    // ---- stage A tile: Hin[m0+r][k] -> fp16, swizzle kg ^= (row&7) ----
    {
        const int r0  = tid >> 6;         // 0..3
        const int kk  = (tid & 63) * 4;   // 0..252
        const int kg  = kk >> 3;
        const int klo = kk & 7;           // 0 or 4
#pragma unroll
        for (int p = 0; p < 16; ++p) {
            int row = p * 4 + r0;
            float4 v = *(const float4*)(Hin + (size_t)(m0 + row) * 256 + kk);
            uint2 pk;
            pk.x = (uint)f16bits(v.x) | ((uint)f16bits(v.y) << 16);
            pk.y = (uint)f16bits(v.z) | ((uint)f16bits(v.w) << 16);
            *(uint2*)&Ah[row * 256 + (kg ^ (row & 7)) * 8 + klo] = pk;
        }
    }

    f4v acc[4][4];
#pragma unroll
    for (int a = 0; a < 4; ++a)
#pragma unroll
        for (int b = 0; b < 4; ++b) acc[a][b] = (f4v){0.f, 0.f, 0.f, 0.f};

    h8v afc[4];   // cached A frags for current ki

#pragma unroll 1
    for (int t = 0; t < 64; ++t) {
        const int cur = t & 1;
        __syncthreads();   // publishes Bh[cur] (+ A tile at t=0)
        if (t < 63) {
            const int tn  = t + 1;
            const int en  = tn & 7;
            const int ki0 = (tn >> 3) * 32;
#pragma unroll
            for (int q = 0; q < 4; ++q)
                GL2LDS16(Wh + (size_t)en * 65536 + bgoff[q] + ki0,
                         &Bh[cur ^ 1][(q * 256 + wid * 64) * 8]);
        }
        if ((t & 7) == 0) {
            const int kg0 = (t >> 3) * 4;
#pragma unroll
            for (int im = 0; im < 4; ++im) {
                int row = im * 16 + fr;
                afc[im] = *(const h8v*)&Ah[row * 256 + ((kg0 + kgl) ^ (row & 7)) * 8];
            }
        }
        const int e = t & 7;
        h8v as[4];
#pragma unroll
        for (int im = 0; im < 4; ++im) {
            _Float16 ah = (_Float16)areg[im][e];
            as[im] = afc[im] * ah;           // 4x v_pk_mul_f16
        }
        h8v bf[4];
#pragma unroll
        for (int in = 0; in < 4; ++in)
            bf[in] = *(const h8v*)&Bh[cur][boff[in]];
#pragma unroll
        for (int im = 0; im < 4; ++im)
#pragma unroll
            for (int in = 0; in < 4; ++in)
                acc[im][in] = __builtin_amdgcn_mfma_f32_16x16x32_f16(as[im], bf[in], acc[im][in], 0, 0, 0);
    }

    // ---- epilogue: + sum_k alpha[b,k]*bias[k,o], optional relu, f32 store ----
    float bv[4][8];
#pragma unroll
    for (int in = 0; in < 4; ++in) {
        int col = wcol0 + in * 16 + fr;
#pragma unroll
        for (int k = 0; k < 8; ++k) bv[in][k] = bias[k * 256 + col];
    }
#pragma unroll
    for (int im = 0; im < 4; ++im) {
#pragma unroll
        for (int j = 0; j < 4; ++j) {
            int row = m0 + im * 16 + kgl * 4 + j;
            const float4* ap = (const float4*)(alpha + (size_t)row * 8);
            float4 a0 = ap[0], a1 = ap[1];
            float a8[8] = {a0.x, a0.y, a0.z, a0.w, a1.x, a1.y, a1.z, a1.w};
#pragma unroll
            for (int in = 0; in < 4; ++in) {
                int col = wcol0 + in * 16 + fr;
                float be = 0.f;
#pragma unroll
                for (int k = 0; k < 8; ++k) be = fmaf(a8[k], bv[in][k], be);
                float v = acc[im][in][j] + be;
                if (RELU) v = fmaxf(v, 0.f);
                Hout[(size_t)row * 256 + col] = v;
            }
        }
    }
}

extern "C" void kernel_launch(void* const* d_in, const int* in_sizes, int n_in,
                              void* d_out, int out_size, void* d_ws, size_t ws_size,
                              hipStream_t stream)
{
    const float* x      = (const float*)d_in[0];
    const float* gW     = (const float*)d_in[1];
    const float* gb     = (const float*)d_in[2];
    const float* blockW = (const float*)d_in[3];
    const float* blockB = (const float*)d_in[4];
    const float* outW   = (const float*)d_in[5];
    const float* outB   = (const float*)d_in[6];
    float* out = (float*)d_out;

    char* ws = (char*)d_ws;
    float*  alpha = (float*)ws;                 // 32768*8*4 = 1 MB
    ushort* Wh    = (ushort*)(ws + (1 << 20));  // 40*65536*2B = 5.25 MB

    prep_weights<<<640, 256, 0, stream>>>(blockW, outW, Wh);
    gate_kernel<<<8192, 256, 0, stream>>>(x, gW, gb, alpha);

    const size_t WL = (size_t)8 * 65536;
    moie_gemm<true ><<<512, 256, 0, stream>>>(x,   out, Wh,          blockB,            alpha);
    moie_gemm<true ><<<512, 256, 0, stream>>>(out, out, Wh + 1 * WL, blockB + 1 * 2048, alpha);
    moie_gemm<true ><<<512, 256, 0, stream>>>(out, out, Wh + 2 * WL, blockB + 2 * 2048, alpha);
    moie_gemm<true ><<<512, 256, 0, stream>>>(out, out, Wh + 3 * WL, blockB + 3 * 2048, alpha);
    moie_gemm<false><<<512, 256, 0, stream>>>(out, out, Wh + 4 * WL, outB,              alpha);
}